// Round 7
// baseline (1608.869 us; speedup 1.0000x reference)
//
#include <hip/hip_runtime.h>
#include <stdint.h>

#define NLAYER 5
#define EMB    300
#define EMBP   320
#define EMBP2  384
#define HID    600
#define HIDP   640
#define BNEPS  1e-5f

typedef __attribute__((ext_vector_type(8))) __bf16 bfrag;
typedef __attribute__((ext_vector_type(8))) short s16x8;
typedef __attribute__((ext_vector_type(4))) float f32x4;

__device__ __forceinline__ float b2f(unsigned short u){
  union { unsigned int i; float f; } v; v.i = ((unsigned int)u) << 16; return v.f;
}
__device__ __forceinline__ unsigned short f2b(float f){
  unsigned int u = __float_as_uint(f);
  u += 0x7FFFu + ((u >> 16) & 1u);
  return (unsigned short)(u >> 16);
}
__device__ __forceinline__ void gload16(const void* g, void* l){
  __builtin_amdgcn_global_load_lds(
      (const __attribute__((address_space(1))) void*)g,
      (__attribute__((address_space(3))) void*)l,
      16, 0, 0);
}

// ---------------- setup kernels ----------------

__global__ void k_zero(unsigned int* __restrict__ p, int n){
  int i = blockIdx.x*blockDim.x + threadIdx.x;
  if (i < n) p[i] = 0u;
}

__global__ void k_hist(const int* __restrict__ ei, int E, int N, int* __restrict__ deg){
  int e = blockIdx.x*blockDim.x + threadIdx.x;
  if (e >= E + N) return;
  int dst = (e < E) ? ei[E + e] : (e - E);
  atomicAdd(&deg[dst], 1);
}

// ---- fast 3-phase exclusive scan of deg[0..N) -> rowptr/cursor ----
__global__ void k_scanA(const int* __restrict__ deg, int* __restrict__ bsum, int N){
  __shared__ int sd[256];
  const int tid = threadIdx.x;
  const int base = blockIdx.x*1024 + tid*4;
  int s = 0;
#pragma unroll
  for (int j = 0; j < 4; j++){ int i = base + j; if (i < N) s += deg[i]; }
  sd[tid] = s; __syncthreads();
  for (int off = 128; off > 0; off >>= 1){
    if (tid < off) sd[tid] += sd[tid+off];
    __syncthreads();
  }
  if (tid == 0) bsum[blockIdx.x] = sd[0];
}

__global__ void k_scanB(const int* __restrict__ bsum, int* __restrict__ boff,
                        int* __restrict__ rowptrN, int NBLK){
  const int lane = threadIdx.x;   // 64 threads
  int carry = 0;
  for (int c = 0; c < NBLK; c += 64){
    int idx = c + lane;
    int v = (idx < NBLK) ? bsum[idx] : 0;
    int incl = v;
    for (int off = 1; off < 64; off <<= 1){
      int t = __shfl_up(incl, off);
      if (lane >= off) incl += t;
    }
    if (idx < NBLK) boff[idx] = carry + incl - v;
    carry += __shfl(incl, 63);
  }
  if (lane == 0) *rowptrN = carry;
}

__global__ void k_scanC(const int* __restrict__ deg, const int* __restrict__ boff,
                        int* __restrict__ rowptr, int* __restrict__ cursor, int N){
  __shared__ int ts[256];
  const int tid = threadIdx.x;
  const int base = blockIdx.x*1024 + tid*4;
  int v[4]; int s = 0;
#pragma unroll
  for (int j = 0; j < 4; j++){ int i = base + j; v[j] = (i < N) ? deg[i] : 0; s += v[j]; }
  ts[tid] = s; __syncthreads();
  for (int off = 1; off < 256; off <<= 1){
    int t = (tid >= off) ? ts[tid-off] : 0;
    __syncthreads();
    ts[tid] += t;
    __syncthreads();
  }
  int excl = ((tid > 0) ? ts[tid-1] : 0) + boff[blockIdx.x];
#pragma unroll
  for (int j = 0; j < 4; j++){
    int i = base + j;
    if (i < N){ rowptr[i] = excl; cursor[i] = excl; }
    excl += v[j];
  }
}

__global__ void k_fill(const int* __restrict__ ei, const int* __restrict__ ea,
                       int E, int N, int* __restrict__ cursor,
                       unsigned int* __restrict__ entries)
{
  int e = blockIdx.x*blockDim.x + threadIdx.x;
  if (e >= E + N) return;
  int src, dst, bt, bd;
  if (e < E) { src = ei[e]; dst = ei[E + e]; bt = ea[2*e]; bd = ea[2*e + 1]; }
  else       { src = e - E; dst = src;       bt = 4;       bd = 0; }
  int pos = atomicAdd(&cursor[dst], 1);
  entries[pos] = (unsigned)src | ((unsigned)bt << 20) | ((unsigned)bd << 24);
}

// W: [NLAYER][K][Ncol] f32 -> WT: [NLAYER][Np][Kp] bf16 (transposed, zero-padded)
__global__ void k_prep_w(const float* __restrict__ W, unsigned short* __restrict__ WT,
                         int K, int Ncol, int Kp, int Np)
{
  int i = blockIdx.x*blockDim.x + threadIdx.x;
  int total = NLAYER * Np * Kp;
  if (i >= total) return;
  int l = i / (Np * Kp);
  int rem = i - l * (Np * Kp);
  int n = rem / Kp;
  int k = rem - n * Kp;
  unsigned short v = 0;
  if (n < Ncol && k < K) v = f2b(W[(size_t)l*K*Ncol + (size_t)k*Ncol + n]);
  WT[i] = v;
}

__global__ void k_pad(const float* __restrict__ src, unsigned short* __restrict__ dst,
                      int R, int SC, int DC)
{
  int i = blockIdx.x*blockDim.x + threadIdx.x;
  if (i >= R * DC) return;
  int r = i / DC, c = i - r * DC;
  dst[i] = (c < SC) ? f2b(src[r*SC + c]) : (unsigned short)0;
}

__global__ void k_padb(const float* __restrict__ src, float* __restrict__ dst,
                       int R, int SC, int DC)
{
  int i = blockIdx.x*blockDim.x + threadIdx.x;
  if (i >= R * DC) return;
  int r = i / DC, c = i - r * DC;
  dst[i] = (c < SC) ? src[r*SC + c] : 0.f;
}

// h0 (f32) written straight into dout: dout[n][c] = xe1[x0][c] + xe2[x1][c]
__global__ void k_h0f(const int* __restrict__ x, const float* __restrict__ xe1,
                      const float* __restrict__ xe2, float* __restrict__ dout, int N){
  int i = blockIdx.x*blockDim.x + threadIdx.x;
  if (i >= N*EMB) return;
  int n = i / EMB, c = i - n*EMB;
  dout[i] = xe1[x[2*n]*EMB + c] + xe2[x[2*n+1]*EMB + c];
}

// ---------------- aggregation: one wave per node, gather from f32 dout ----------------
// BN=false (layer 0): raw rows.  BN=true: row -> relu(row*scl + sft) per element.
// aggr[n] (bf16, EMBP cols) = sum_edges transform(dout[src]) + sum_t cnt*t1[t] + cnt*t2[d]
template<bool BN>
__global__ __launch_bounds__(256) void k_aggr(
    const float* __restrict__ src,
    const int* __restrict__ rowptr,
    const unsigned int* __restrict__ entries,
    const unsigned short* __restrict__ t1,   // [6][EMBP] bf16
    const unsigned short* __restrict__ t2,   // [3][EMBP] bf16
    const float* __restrict__ scl, const float* __restrict__ sft,
    unsigned short* __restrict__ aggr, int N, int Mp)
{
  const int w = threadIdx.x >> 6, lane = threadIdx.x & 63;
  const int n = blockIdx.x * 4 + w;
  if (n >= Mp || lane >= 40) return;
  const int c0 = lane * 8;
  const bool lo = (c0 + 4) <= EMB;
  const bool hi = (c0 + 8) <= EMB;
  float s[8] = {0.f,0.f,0.f,0.f,0.f,0.f,0.f,0.f};
  if (n < N) {
    float sc[8], sf[8];
    if (BN) {
#pragma unroll
      for (int j = 0; j < 8; j++){
        int c = c0 + j;
        sc[j] = (c < EMB) ? scl[c] : 0.f;
        sf[j] = (c < EMB) ? sft[c] : 0.f;
      }
    }
    const int beg = rowptr[n], end = rowptr[n+1];
    int c6[6] = {0,0,0,0,0,0};
    int c3[3] = {0,0,0};
    int e = beg;
    for (; e + 4 <= end; e += 4) {
      unsigned p[4] = {entries[e], entries[e+1], entries[e+2], entries[e+3]};
      float v[4][8];
#pragma unroll
      for (int q = 0; q < 4; q++){
        const float* row = src + (size_t)(p[q] & 0xFFFFF)*EMB + c0;
        f32x4 a = lo ? *(const f32x4*)row     : (f32x4){0,0,0,0};
        f32x4 b = hi ? *(const f32x4*)(row+4) : (f32x4){0,0,0,0};
#pragma unroll
        for (int j = 0; j < 4; j++){ v[q][j] = a[j]; v[q][4+j] = b[j]; }
      }
#pragma unroll
      for (int q = 0; q < 4; q++){
        const int bt = (p[q] >> 20) & 7, bd = (p[q] >> 24) & 3;
#pragma unroll
        for (int t = 0; t < 6; t++) c6[t] += (bt == t);
#pragma unroll
        for (int t = 0; t < 3; t++) c3[t] += (bd == t);
      }
#pragma unroll
      for (int q = 0; q < 4; q++)
#pragma unroll
        for (int j = 0; j < 8; j++){
          float xv = v[q][j];
          if (BN) xv = fmaxf(fmaf(xv, sc[j], sf[j]), 0.f);
          s[j] += xv;
        }
    }
    for (; e < end; ++e) {
      const unsigned p = entries[e];
      const float* row = src + (size_t)(p & 0xFFFFF)*EMB + c0;
      f32x4 a = lo ? *(const f32x4*)row     : (f32x4){0,0,0,0};
      f32x4 b = hi ? *(const f32x4*)(row+4) : (f32x4){0,0,0,0};
      const int bt = (p >> 20) & 7, bd = (p >> 24) & 3;
#pragma unroll
      for (int t = 0; t < 6; t++) c6[t] += (bt == t);
#pragma unroll
      for (int t = 0; t < 3; t++) c3[t] += (bd == t);
#pragma unroll
      for (int j = 0; j < 8; j++){
        float xv = (j < 4) ? a[j] : b[j-4];
        if (BN) xv = fmaxf(fmaf(xv, sc[j], sf[j]), 0.f);
        s[j] += xv;
      }
    }
#pragma unroll
    for (int t = 0; t < 6; t++) if (c6[t]) {
      s16x8 tv = *(const s16x8*)&t1[t*EMBP + c0];
      const float f = (float)c6[t];
#pragma unroll
      for (int j = 0; j < 8; j++) s[j] += f * b2f((unsigned short)tv[j]);
    }
#pragma unroll
    for (int t = 0; t < 3; t++) if (c3[t]) {
      s16x8 tv = *(const s16x8*)&t2[t*EMBP + c0];
      const float f = (float)c3[t];
#pragma unroll
      for (int j = 0; j < 8; j++) s[j] += f * b2f((unsigned short)tv[j]);
    }
  }
  s16x8 o;
#pragma unroll
  for (int j = 0; j < 8; j++) o[j] = (short)f2b(s[j]);
  *(s16x8*)&aggr[(size_t)n*EMBP + c0] = o;
}

// ---------------- GEMM: 128x128 tile, 4 waves 2x2, BK=64, XOR-8 swizzle ----------------
// FIRST: C=bf16 relu -> hid (stride HIDP, chunk-local rows). else: C=f32 d_out, masked.
template<int KP, bool FIRST>
__global__ __launch_bounds__(256) void k_gemm(
    const unsigned short* __restrict__ A,
    const unsigned short* __restrict__ Bt,
    const float* __restrict__ bias,
    void* __restrict__ Cv,
    int nBase, int N)
{
  __shared__ __align__(16) unsigned short As[128*64];
  __shared__ __align__(16) unsigned short Bs[128*64];
  const int tid = threadIdx.x;
  const int w = tid >> 6, lane = tid & 63;
  const int wr = w >> 1, wc = w & 1;
  const int m0 = blockIdx.x * 128;
  const int n0 = blockIdx.y * 128;
  const int cl = lane & 15, kg = lane >> 4;

  // staging map: 4 rounds x 256 threads cover 128 rows x 8 segs (16B each).
  // LDS dest linear (wave-uniform base + lane*16); global source pre-swizzled
  // seg_g = seg ^ (row&7)  (both-sides involution, rule #21).
  const unsigned short* ag[4]; const unsigned short* bg[4]; int ldst[4];
#pragma unroll
  for (int i = 0; i < 4; i++){
    const int id = i*256 + tid;
    const int row = id >> 3, seg = id & 7;
    const int col = (seg ^ (row & 7)) * 8;
    ag[i] = A  + (size_t)(m0 + row)*KP + col;
    bg[i] = Bt + (size_t)(n0 + row)*KP + col;
    ldst[i] = id * 8;
  }

  f32x4 acc[4][4];
#pragma unroll
  for (int i = 0; i < 4; i++)
#pragma unroll
    for (int j = 0; j < 4; j++)
      acc[i][j] = (f32x4){0.f, 0.f, 0.f, 0.f};

  for (int k0 = 0; k0 < KP; k0 += 64) {
#pragma unroll
    for (int i = 0; i < 4; i++) gload16(ag[i] + k0, &As[ldst[i]]);
#pragma unroll
    for (int i = 0; i < 4; i++) gload16(bg[i] + k0, &Bs[ldst[i]]);
    __syncthreads();
    bfrag af[4][2], bf[4][2];
#pragma unroll
    for (int mf = 0; mf < 4; mf++){
      const int row = wr*64 + mf*16 + cl;
#pragma unroll
      for (int hh = 0; hh < 2; hh++)
        af[mf][hh] = *(const bfrag*)&As[row*64 + (((kg + 4*hh) ^ (cl & 7)) * 8)];
    }
#pragma unroll
    for (int nf = 0; nf < 4; nf++){
      const int row = wc*64 + nf*16 + cl;
#pragma unroll
      for (int hh = 0; hh < 2; hh++)
        bf[nf][hh] = *(const bfrag*)&Bs[row*64 + (((kg + 4*hh) ^ (cl & 7)) * 8)];
    }
#pragma unroll
    for (int mf = 0; mf < 4; mf++)
#pragma unroll
      for (int nf = 0; nf < 4; nf++){
        acc[mf][nf] = __builtin_amdgcn_mfma_f32_16x16x32_bf16(af[mf][0], bf[nf][0], acc[mf][nf], 0, 0, 0);
        acc[mf][nf] = __builtin_amdgcn_mfma_f32_16x16x32_bf16(af[mf][1], bf[nf][1], acc[mf][nf], 0, 0, 0);
      }
    __syncthreads();
  }

  const int rg = lane >> 4;
#pragma unroll
  for (int mf = 0; mf < 4; mf++) {
#pragma unroll
    for (int nf = 0; nf < 4; nf++) {
      const int col  = n0 + wc*64 + nf*16 + cl;
      const int row0 = m0 + wr*64 + mf*16 + rg*4;
      f32x4 v = acc[mf][nf];
      if (FIRST) {
        const float bv = bias[col];
#pragma unroll
        for (int r = 0; r < 4; r++)
          ((unsigned short*)Cv)[(size_t)(row0 + r)*HIDP + col] = f2b(fmaxf(v[r] + bv, 0.f));
      } else {
        if (col < EMB) {
          const float bv = bias[col];
#pragma unroll
          for (int r = 0; r < 4; r++) {
            const int grow = nBase + row0 + r;
            if (grow < N)
              ((float*)Cv)[(size_t)grow*EMB + col] = v[r] + bv;
          }
        }
      }
    }
  }
}

// ---------------- BatchNorm stats (deterministic) ----------------

__global__ void k_bnstat(const float* __restrict__ out, float* __restrict__ part, int N)
{
  const int c = threadIdx.x;   // 0..319
  float s = 0.f, s2 = 0.f;
  if (c < EMB) {
    for (int r = blockIdx.x; r < N; r += gridDim.x) {
      float v = out[(size_t)r*EMB + c];
      s += v; s2 += v*v;
    }
  }
  part[blockIdx.x*(2*EMBP) + c]        = s;
  part[blockIdx.x*(2*EMBP) + EMBP + c] = s2;
}

__global__ void k_bnfin(const float* __restrict__ part,
                        const float* __restrict__ gamma,
                        const float* __restrict__ beta,
                        float* __restrict__ scl, float* __restrict__ sft, int N, int NB)
{
  const int c = threadIdx.x;
  if (c >= EMBP) return;
  float s = 0.f, s2 = 0.f;
  for (int b = 0; b < NB; b++) {
    s  += part[b*(2*EMBP) + c];
    s2 += part[b*(2*EMBP) + EMBP + c];
  }
  if (c < EMB) {
    float mean = s / (float)N;
    float var  = fmaxf(s2 / (float)N - mean*mean, 0.f);
    float sc = gamma[c] * rsqrtf(var + BNEPS);
    scl[c] = sc;
    sft[c] = beta[c] - mean*sc;
  } else { scl[c] = 0.f; sft[c] = 0.f; }
}

// last layer: dout = dout*scl + sft (no relu), in place
__global__ void k_bnlast(float* __restrict__ out, const float* __restrict__ scl,
                         const float* __restrict__ sft, int N){
  int i = blockIdx.x*blockDim.x + threadIdx.x;
  if (i >= N*EMB) return;
  int c = i % EMB;
  out[i] = out[i]*scl[c] + sft[c];
}

// ---------------- host ----------------

extern "C" void kernel_launch(void* const* d_in, const int* in_sizes, int n_in,
                              void* d_out, int out_size, void* d_ws, size_t ws_size,
                              hipStream_t stream)
{
  (void)n_in; (void)out_size;
  const int* x  = (const int*)d_in[0];
  const int* ei = (const int*)d_in[1];
  const int* ea = (const int*)d_in[2];
  const float* xe1 = (const float*)d_in[3];
  const float* xe2 = (const float*)d_in[4];
  const float* ee1 = (const float*)d_in[5];
  const float* ee2 = (const float*)d_in[6];
  const float* W1  = (const float*)d_in[7];
  const float* b1  = (const float*)d_in[8];
  const float* W2  = (const float*)d_in[9];
  const float* b2  = (const float*)d_in[10];
  const float* gam = (const float*)d_in[11];
  const float* bet = (const float*)d_in[12];

  const int N  = in_sizes[0] / 2;
  const int E  = in_sizes[1] / 2;
  const int EN = E + N;
  const int Mp = ((N + 127) / 128) * 128;
  const int NBLK = (N + 1023) / 1024;

  float* dout = (float*)d_out;

  char* ws = (char*)d_ws;
  size_t off = 0;
  auto alloc = [&](size_t bytes){ size_t o = off; off = (off + bytes + 255) & ~(size_t)255; return o; };

  unsigned short* aggr   = (unsigned short*)(ws + alloc((size_t)Mp*EMBP*2));
  unsigned int*  entries = (unsigned int*)(ws + alloc((size_t)EN*4));
  int* rowptr            = (int*)(ws + alloc((size_t)(N+1)*4));
  int* cursor            = (int*)(ws + alloc((size_t)N*4));
  int* deg               = (int*)(ws + alloc((size_t)N*4));
  int* bsum              = (int*)(ws + alloc((size_t)NBLK*4));
  int* boff              = (int*)(ws + alloc((size_t)NBLK*4));
  unsigned short* W1T    = (unsigned short*)(ws + alloc((size_t)NLAYER*HIDP*EMBP*2));
  unsigned short* W2T    = (unsigned short*)(ws + alloc((size_t)NLAYER*EMBP2*HIDP*2));
  unsigned short* e1p    = (unsigned short*)(ws + alloc((size_t)NLAYER*6*EMBP*2));
  unsigned short* e2p    = (unsigned short*)(ws + alloc((size_t)NLAYER*3*EMBP*2));
  float* b1p             = (float*)(ws + alloc((size_t)NLAYER*HIDP*4));
  float* b2p             = (float*)(ws + alloc((size_t)NLAYER*EMBP*4));
  float* part            = (float*)(ws + alloc((size_t)256*2*EMBP*4));
  float* scl             = (float*)(ws + alloc((size_t)EMBP*4));
  float* sft             = (float*)(ws + alloc((size_t)EMBP*4));

  if (off >= ws_size) return;
  size_t avail = ws_size - off;
  size_t maxrows = avail / ((size_t)HIDP*2);
  if (maxrows < 128) return;
  int CH = (maxrows >= (size_t)Mp) ? Mp : (int)(maxrows & ~(size_t)127);
  unsigned short* hidc = (unsigned short*)(ws + off);

  // CSR build
  k_zero<<<(N+255)/256, 256, 0, stream>>>((unsigned int*)deg, N);
  k_hist<<<(EN+255)/256, 256, 0, stream>>>(ei, E, N, deg);
  k_scanA<<<NBLK, 256, 0, stream>>>(deg, bsum, N);
  k_scanB<<<1, 64, 0, stream>>>(bsum, boff, rowptr + N, NBLK);
  k_scanC<<<NBLK, 256, 0, stream>>>(deg, boff, rowptr, cursor, N);
  k_fill<<<(EN+255)/256, 256, 0, stream>>>(ei, ea, E, N, cursor, entries);

  // weight/table prep
  {
    int tot1 = NLAYER*HIDP*EMBP;
    k_prep_w<<<(tot1+255)/256, 256, 0, stream>>>(W1, W1T, EMB, HID, EMBP, HIDP);
    int tot2 = NLAYER*EMBP2*HIDP;
    k_prep_w<<<(tot2+255)/256, 256, 0, stream>>>(W2, W2T, HID, EMB, HIDP, EMBP2);
  }
  k_pad <<<((NLAYER*6*EMBP)+255)/256, 256, 0, stream>>>(ee1, e1p, NLAYER*6, EMB, EMBP);
  k_pad <<<((NLAYER*3*EMBP)+255)/256, 256, 0, stream>>>(ee2, e2p, NLAYER*3, EMB, EMBP);
  k_padb<<<((NLAYER*HIDP)+255)/256, 256, 0, stream>>>(b1, b1p, NLAYER, HID, HIDP);
  k_padb<<<((NLAYER*EMBP)+255)/256, 256, 0, stream>>>(b2, b2p, NLAYER, EMB, EMBP);

  // h0 in f32, straight into dout
  k_h0f<<<((N*EMB)+255)/256, 256, 0, stream>>>(x, xe1, xe2, dout, N);

  for (int l = 0; l < NLAYER; ++l) {
    if (l == 0)
      k_aggr<false><<<Mp/4, 256, 0, stream>>>(dout, rowptr, entries,
          e1p + (size_t)l*6*EMBP, e2p + (size_t)l*3*EMBP,
          nullptr, nullptr, aggr, N, Mp);
    else
      k_aggr<true><<<Mp/4, 256, 0, stream>>>(dout, rowptr, entries,
          e1p + (size_t)l*6*EMBP, e2p + (size_t)l*3*EMBP,
          scl, sft, aggr, N, Mp);

    for (int base = 0; base < Mp; base += CH) {
      const int rows = (Mp - base < CH) ? (Mp - base) : CH;
      dim3 g1(rows/128, HIDP/128);
      k_gemm<EMBP, true><<<g1, 256, 0, stream>>>(
          aggr + (size_t)base*EMBP, W1T + (size_t)l*HIDP*EMBP,
          b1p + (size_t)l*HIDP, hidc, 0, N);
      dim3 g2(rows/128, EMBP2/128);
      k_gemm<HIDP, false><<<g2, 256, 0, stream>>>(
          hidc, W2T + (size_t)l*EMBP2*HIDP,
          b2p + (size_t)l*EMBP, dout, base, N);
    }
    k_bnstat<<<256, EMBP, 0, stream>>>(dout, part, N);
    k_bnfin<<<1, EMBP, 0, stream>>>(part, gam + (size_t)l*EMB, bet + (size_t)l*EMB, scl, sft, N, 256);
  }
  // final BN (no relu), in place on dout
  k_bnlast<<<((N*EMB)+255)/256, 256, 0, stream>>>(dout, scl, sft, N);
}

// Round 9
// 1313.748 us; speedup vs baseline: 1.2246x; 1.2246x over previous
//
#include <hip/hip_runtime.h>
#include <stdint.h>

#define NLAYER 5
#define EMB    300
#define EMBP   320
#define EMBP2  384
#define HID    600
#define HIDP   640
#define BNEPS  1e-5f

typedef _Float16 f16;
typedef __attribute__((ext_vector_type(8))) _Float16 hfrag;
typedef __attribute__((ext_vector_type(4))) float f32x4;

__device__ __forceinline__ void gload16(const void* g, void* l){
  __builtin_amdgcn_global_load_lds(
      (const __attribute__((address_space(1))) void*)g,
      (__attribute__((address_space(3))) void*)l,
      16, 0, 0);
}

// ---------------- setup kernels ----------------

__global__ void k_zero(unsigned int* __restrict__ p, int n){
  int i = blockIdx.x*blockDim.x + threadIdx.x;
  if (i < n) p[i] = 0u;
}

__global__ void k_hist(const int* __restrict__ ei, int E, int N, int* __restrict__ deg){
  int e = blockIdx.x*blockDim.x + threadIdx.x;
  if (e >= E + N) return;
  int dst = (e < E) ? ei[E + e] : (e - E);
  atomicAdd(&deg[dst], 1);
}

// ---- 3-phase exclusive scan ----
__global__ void k_scanA(const int* __restrict__ deg, int* __restrict__ bsum, int N){
  __shared__ int sd[256];
  const int tid = threadIdx.x;
  const int base = blockIdx.x*1024 + tid*4;
  int s = 0;
#pragma unroll
  for (int j = 0; j < 4; j++){ int i = base + j; if (i < N) s += deg[i]; }
  sd[tid] = s; __syncthreads();
  for (int off = 128; off > 0; off >>= 1){
    if (tid < off) sd[tid] += sd[tid+off];
    __syncthreads();
  }
  if (tid == 0) bsum[blockIdx.x] = sd[0];
}

__global__ void k_scanB(const int* __restrict__ bsum, int* __restrict__ boff,
                        int* __restrict__ rowptrN, int NBLK){
  const int lane = threadIdx.x;   // 64 threads
  int carry = 0;
  for (int c = 0; c < NBLK; c += 64){
    int idx = c + lane;
    int v = (idx < NBLK) ? bsum[idx] : 0;
    int incl = v;
    for (int off = 1; off < 64; off <<= 1){
      int t = __shfl_up(incl, off);
      if (lane >= off) incl += t;
    }
    if (idx < NBLK) boff[idx] = carry + incl - v;
    carry += __shfl(incl, 63);
  }
  if (lane == 0) *rowptrN = carry;
}

__global__ void k_scanC(const int* __restrict__ deg, const int* __restrict__ boff,
                        int* __restrict__ rowptr, int* __restrict__ cursor, int N){
  __shared__ int ts[256];
  const int tid = threadIdx.x;
  const int base = blockIdx.x*1024 + tid*4;
  int v[4]; int s = 0;
#pragma unroll
  for (int j = 0; j < 4; j++){ int i = base + j; v[j] = (i < N) ? deg[i] : 0; s += v[j]; }
  ts[tid] = s; __syncthreads();
  for (int off = 1; off < 256; off <<= 1){
    int t = (tid >= off) ? ts[tid-off] : 0;
    __syncthreads();
    ts[tid] += t;
    __syncthreads();
  }
  int excl = ((tid > 0) ? ts[tid-1] : 0) + boff[blockIdx.x];
#pragma unroll
  for (int j = 0; j < 4; j++){
    int i = base + j;
    if (i < N){ rowptr[i] = excl; cursor[i] = excl; }
    excl += v[j];
  }
}

__global__ void k_fill(const int* __restrict__ ei, const int* __restrict__ ea,
                       int E, int N, int* __restrict__ cursor,
                       unsigned int* __restrict__ entries)
{
  int e = blockIdx.x*blockDim.x + threadIdx.x;
  if (e >= E + N) return;
  int src, dst, bt, bd;
  if (e < E) { src = ei[e]; dst = ei[E + e]; bt = ea[2*e]; bd = ea[2*e + 1]; }
  else       { src = e - E; dst = src;       bt = 4;       bd = 0; }
  int pos = atomicAdd(&cursor[dst], 1);
  entries[pos] = (unsigned)src | ((unsigned)bt << 20) | ((unsigned)bd << 24);
}

// W: [NLAYER][K][Ncol] f32 -> WT: [NLAYER][Np][Kp] f16 (transposed, zero-padded)
__global__ void k_prep_w(const float* __restrict__ W, f16* __restrict__ WT,
                         int K, int Ncol, int Kp, int Np)
{
  int i = blockIdx.x*blockDim.x + threadIdx.x;
  int total = NLAYER * Np * Kp;
  if (i >= total) return;
  int l = i / (Np * Kp);
  int rem = i - l * (Np * Kp);
  int n = rem / Kp;
  int k = rem - n * Kp;
  f16 v = (f16)0.f;
  if (n < Ncol && k < K) v = (f16)W[(size_t)l*K*Ncol + (size_t)k*Ncol + n];
  WT[i] = v;
}

// [R][SC] f32 -> [R][DC] f32 zero-padded
__global__ void k_padb(const float* __restrict__ src, float* __restrict__ dst,
                       int R, int SC, int DC)
{
  int i = blockIdx.x*blockDim.x + threadIdx.x;
  if (i >= R * DC) return;
  int r = i / DC, c = i - r * DC;
  dst[i] = (c < SC) ? src[r*SC + c] : 0.f;
}

// h0 f16 padded: h[n][c] = f16(xe1[x0][c] + xe2[x1][c])
__global__ void k_h0(const int* __restrict__ x, const float* __restrict__ xe1,
                     const float* __restrict__ xe2, f16* __restrict__ h, int N)
{
  const int w = threadIdx.x >> 6, lane = threadIdx.x & 63;
  const int n = blockIdx.x * 4 + w;
  if (n >= N || lane >= 40) return;
  const int c0 = lane * 8;
  const bool lo = (c0 + 4) <= EMB;
  const bool hi = (c0 + 8) <= EMB;
  const float* r1 = xe1 + (size_t)x[2*n]*EMB + c0;
  const float* r2 = xe2 + (size_t)x[2*n+1]*EMB + c0;
  f32x4 a1 = lo ? *(const f32x4*)r1     : (f32x4){0,0,0,0};
  f32x4 a2 = hi ? *(const f32x4*)(r1+4) : (f32x4){0,0,0,0};
  f32x4 b1 = lo ? *(const f32x4*)r2     : (f32x4){0,0,0,0};
  f32x4 b2 = hi ? *(const f32x4*)(r2+4) : (f32x4){0,0,0,0};
  hfrag o;
#pragma unroll
  for (int j = 0; j < 4; j++){
    o[j]   = (f16)(a1[j] + b1[j]);
    o[4+j] = (f16)(a2[j] + b2[j]);
  }
  *(hfrag*)&h[(size_t)n*EMBP + c0] = o;
}

// ---------------- aggregation: one wave per node, f16 h gather ----------------
// 8-wide predicated batches (wave-uniform mask): 1 latency round for deg<=8 (~93%).
__global__ __launch_bounds__(256) void k_aggr(
    const f16* __restrict__ h,                  // [N][EMBP] f16
    const int* __restrict__ rowptr,
    const unsigned int* __restrict__ entries,
    const float* __restrict__ t1,               // [6][EMBP] f32 padded
    const float* __restrict__ t2,               // [3][EMBP] f32 padded
    f16* __restrict__ aggr, int N, int Mp)
{
  const int w = threadIdx.x >> 6, lane = threadIdx.x & 63;
  const int n = blockIdx.x * 4 + w;
  if (n >= Mp || lane >= 40) return;
  const int c0 = lane * 8;
  float s[8] = {0.f,0.f,0.f,0.f,0.f,0.f,0.f,0.f};
  if (n < N) {
    const int beg = rowptr[n], end = rowptr[n+1];
    int c6[6] = {0,0,0,0,0,0};
    int c3[3] = {0,0,0};
    for (int b0 = beg; b0 < end; b0 += 8) {
      unsigned pe[8]; bool vl[8];
#pragma unroll
      for (int j = 0; j < 8; j++){
        const int idx = b0 + j;
        vl[j] = idx < end;                 // wave-uniform
        pe[j] = entries[vl[j] ? idx : beg];
      }
      hfrag v[8];
#pragma unroll
      for (int j = 0; j < 8; j++)
        v[j] = *(const hfrag*)&h[(size_t)(pe[j] & 0xFFFFF)*EMBP + c0];
#pragma unroll
      for (int j = 0; j < 8; j++){
        if (vl[j]){
          const int bt = (pe[j] >> 20) & 7, bd = (pe[j] >> 24) & 3;
#pragma unroll
          for (int t = 0; t < 6; t++) c6[t] += (bt == t);
#pragma unroll
          for (int t = 0; t < 3; t++) c3[t] += (bd == t);
#pragma unroll
          for (int k = 0; k < 8; k++) s[k] += (float)v[j][k];
        }
      }
    }
#pragma unroll
    for (int t = 0; t < 6; t++) if (c6[t]) {
      const float f = (float)c6[t];
      f32x4 a = *(const f32x4*)&t1[t*EMBP + c0];
      f32x4 b = *(const f32x4*)&t1[t*EMBP + c0 + 4];
#pragma unroll
      for (int k = 0; k < 4; k++){ s[k] += f*a[k]; s[4+k] += f*b[k]; }
    }
#pragma unroll
    for (int t = 0; t < 3; t++) if (c3[t]) {
      const float f = (float)c3[t];
      f32x4 a = *(const f32x4*)&t2[t*EMBP + c0];
      f32x4 b = *(const f32x4*)&t2[t*EMBP + c0 + 4];
#pragma unroll
      for (int k = 0; k < 4; k++){ s[k] += f*a[k]; s[4+k] += f*b[k]; }
    }
  }
  hfrag o;
#pragma unroll
  for (int j = 0; j < 8; j++) o[j] = (f16)s[j];
  *(hfrag*)&aggr[(size_t)n*EMBP + c0] = o;
}

// ---------------- GEMM: 128x128 tile, BK=64, double-buffered, counted vmcnt ----
// FIRST: C = f16 relu -> hid (stride HIDP, chunk-local). else: C = f32 d_out,
// masked, + fused deterministic BN partial stats per (rowblock, colblock).
template<int KP, bool FIRST>
__global__ __launch_bounds__(256) void k_gemm(
    const f16* __restrict__ A,
    const f16* __restrict__ Bt,
    const float* __restrict__ bias,
    void* __restrict__ Cv,
    float* __restrict__ part,
    int nBase, int N)
{
  constexpr int NT = KP / 64;
  __shared__ __align__(16) f16 As[2][128*64];
  __shared__ __align__(16) f16 Bs[2][128*64];
  __shared__ float redS[4][64];
  __shared__ float redQ[4][64];
  const int tid = threadIdx.x;
  const int w = tid >> 6, lane = tid & 63;
  const int wr = w >> 1, wc = w & 1;
  const int m0 = blockIdx.x * 128;
  const int n0 = blockIdx.y * 128;
  const int cl = lane & 15, kg = lane >> 4;

  // 4 rounds x 256 threads cover 128 rows x 8 segs (16B). LDS dest linear;
  // global source pre-swizzled seg_g = seg ^ (row&7) (both-sides, rule #21).
  const f16* ag[4]; const f16* bg[4]; int ldst[4];
#pragma unroll
  for (int i = 0; i < 4; i++){
    const int id = i*256 + tid;
    const int row = id >> 3, seg = id & 7;
    const int col = (seg ^ (row & 7)) * 8;
    ag[i] = A  + (size_t)(m0 + row)*KP + col;
    bg[i] = Bt + (size_t)(n0 + row)*KP + col;
    ldst[i] = id * 8;
  }

  auto STAGE = [&](int bb, int kt){
    const int k0 = kt*64;
#pragma unroll
    for (int i = 0; i < 4; i++) gload16(ag[i] + k0, &As[bb][ldst[i]]);
#pragma unroll
    for (int i = 0; i < 4; i++) gload16(bg[i] + k0, &Bs[bb][ldst[i]]);
  };

  f32x4 acc[4][4];
#pragma unroll
  for (int i = 0; i < 4; i++)
#pragma unroll
    for (int j = 0; j < 4; j++)
      acc[i][j] = (f32x4){0.f, 0.f, 0.f, 0.f};

  STAGE(0, 0);
#pragma unroll
  for (int t = 0; t < NT; ++t){
    const int cur = t & 1;
    if (t + 1 < NT){
      STAGE(cur ^ 1, t + 1);                       // prefetch stays in flight
      asm volatile("s_waitcnt vmcnt(8)" ::: "memory");   // only tile t drained
    } else {
      asm volatile("s_waitcnt vmcnt(0)" ::: "memory");
    }
    __builtin_amdgcn_s_barrier();                  // raw: no vmcnt(0) drain
    hfrag af[4][2], bf[4][2];
#pragma unroll
    for (int mf = 0; mf < 4; mf++){
      const int row = wr*64 + mf*16 + cl;
#pragma unroll
      for (int hh = 0; hh < 2; hh++)
        af[mf][hh] = *(const hfrag*)&As[cur][row*64 + (((kg + 4*hh) ^ (cl & 7)) * 8)];
    }
#pragma unroll
    for (int nf = 0; nf < 4; nf++){
      const int row = wc*64 + nf*16 + cl;
#pragma unroll
      for (int hh = 0; hh < 2; hh++)
        bf[nf][hh] = *(const hfrag*)&Bs[cur][row*64 + (((kg + 4*hh) ^ (cl & 7)) * 8)];
    }
#pragma unroll
    for (int mf = 0; mf < 4; mf++)
#pragma unroll
      for (int nf = 0; nf < 4; nf++){
        acc[mf][nf] = __builtin_amdgcn_mfma_f32_16x16x32_f16(af[mf][0], bf[nf][0], acc[mf][nf], 0, 0, 0);
        acc[mf][nf] = __builtin_amdgcn_mfma_f32_16x16x32_f16(af[mf][1], bf[nf][1], acc[mf][nf], 0, 0, 0);
      }
    __builtin_amdgcn_s_barrier();                  // reads of buf done before re-stage
  }

  const int rg = lane >> 4;
  float ps[4] = {0.f,0.f,0.f,0.f}, pq[4] = {0.f,0.f,0.f,0.f};
#pragma unroll
  for (int mf = 0; mf < 4; mf++) {
#pragma unroll
    for (int nf = 0; nf < 4; nf++) {
      const int col  = n0 + wc*64 + nf*16 + cl;
      const int row0 = m0 + wr*64 + mf*16 + rg*4;
      f32x4 v = acc[mf][nf];
      if (FIRST) {
        const float bv = bias[col];
#pragma unroll
        for (int r = 0; r < 4; r++)
          ((f16*)Cv)[(size_t)(row0 + r)*HIDP + col] = (f16)fmaxf(v[r] + bv, 0.f);
      } else {
        const float bv = bias[col];
#pragma unroll
        for (int r = 0; r < 4; r++) {
          const int grow = nBase + row0 + r;
          if (grow < N) {
            const float o = v[r] + bv;
            if (col < EMB) ((float*)Cv)[(size_t)grow*EMB + col] = o;
            ps[nf] += o; pq[nf] += o*o;
          }
        }
      }
    }
  }

  if (!FIRST) {
    // deterministic reduce: shfl tree over rg, LDS over wr, write per-(gb,colblock)
#pragma unroll
    for (int nf = 0; nf < 4; nf++){
      float s1 = ps[nf], q1 = pq[nf];
      s1 += __shfl_xor(s1, 16); q1 += __shfl_xor(q1, 16);
      s1 += __shfl_xor(s1, 32); q1 += __shfl_xor(q1, 32);
      if (rg == 0){ redS[w][nf*16 + cl] = s1; redQ[w][nf*16 + cl] = q1; }
    }
    __syncthreads();
    if (w < 2 && lane < 16){
      const int gb = (nBase + m0) >> 7;
      float* pS = part + (size_t)gb * (2*EMBP);
#pragma unroll
      for (int nf = 0; nf < 4; nf++){
        const int lc  = nf*16 + lane;
        const int col = n0 + w*64 + nf*16 + lane;
        if (col < EMBP){
          pS[col]        = redS[w][lc] + redS[w+2][lc];
          pS[EMBP + col] = redQ[w][lc] + redQ[w+2][lc];
        }
      }
    }
  }
}

// ---------------- BN finalize + apply ----------------

__global__ void k_bnfin(const float* __restrict__ part,
                        const float* __restrict__ gamma,
                        const float* __restrict__ beta,
                        float* __restrict__ scl, float* __restrict__ sft, int N, int RB)
{
  const int c = threadIdx.x;
  if (c >= EMBP) return;
  float s = 0.f, q = 0.f;
  for (int gb = 0; gb < RB; gb++) {
    s += part[(size_t)gb*(2*EMBP) + c];
    q += part[(size_t)gb*(2*EMBP) + EMBP + c];
  }
  if (c < EMB) {
    float mean = s / (float)N;
    float var  = fmaxf(q / (float)N - mean*mean, 0.f);
    float sc = gamma[c] * rsqrtf(var + BNEPS);
    scl[c] = sc;
    sft[c] = beta[c] - mean*sc;
  } else { scl[c] = 0.f; sft[c] = 0.f; }
}

// mid layers: h[n][c] = f16(relu(dout*scl+sft)), pad cols zero
__global__ void k_bnapply(const float* __restrict__ outv,
                          const float* __restrict__ scl, const float* __restrict__ sft,
                          f16* __restrict__ h, int N)
{
  int i = blockIdx.x*blockDim.x + threadIdx.x;
  if (i >= N * (EMBP/4)) return;
  const int n = i / (EMBP/4);
  const int c = (i - n*(EMBP/4)) * 4;
  f16 o[4];
  if (c < EMB) {   // EMB%4==0: segments fully in or out
    f32x4 v = *(const f32x4*)&outv[(size_t)n*EMB + c];
#pragma unroll
    for (int j = 0; j < 4; j++) o[j] = (f16)fmaxf(v[j]*scl[c+j] + sft[c+j], 0.f);
  } else {
#pragma unroll
    for (int j = 0; j < 4; j++) o[j] = (f16)0.f;
  }
  *(unsigned long long*)&h[(size_t)n*EMBP + c] = *(const unsigned long long*)o;
}

// last layer: dout = dout*scl + sft (no relu), in place
__global__ void k_bnlast(float* __restrict__ out, const float* __restrict__ scl,
                         const float* __restrict__ sft, int N){
  int i = blockIdx.x*blockDim.x + threadIdx.x;
  if (i >= N*EMB) return;
  int c = i % EMB;
  out[i] = out[i]*scl[c] + sft[c];
}

// ---------------- host ----------------

extern "C" void kernel_launch(void* const* d_in, const int* in_sizes, int n_in,
                              void* d_out, int out_size, void* d_ws, size_t ws_size,
                              hipStream_t stream)
{
  (void)n_in; (void)out_size;
  const int* x  = (const int*)d_in[0];
  const int* ei = (const int*)d_in[1];
  const int* ea = (const int*)d_in[2];
  const float* xe1 = (const float*)d_in[3];
  const float* xe2 = (const float*)d_in[4];
  const float* ee1 = (const float*)d_in[5];
  const float* ee2 = (const float*)d_in[6];
  const float* W1  = (const float*)d_in[7];
  const float* b1  = (const float*)d_in[8];
  const float* W2  = (const float*)d_in[9];
  const float* b2  = (const float*)d_in[10];
  const float* gam = (const float*)d_in[11];
  const float* bet = (const float*)d_in[12];

  const int N  = in_sizes[0] / 2;
  const int E  = in_sizes[1] / 2;
  const int EN = E + N;
  const int Mp = ((N + 127) / 128) * 128;
  const int RB = Mp / 128;
  const int NBLK = (N + 1023) / 1024;

  float* dout = (float*)d_out;

  char* ws = (char*)d_ws;
  size_t off = 0;
  auto alloc = [&](size_t bytes){ size_t o = off; off = (off + bytes + 255) & ~(size_t)255; return o; };

  f16* h                 = (f16*)(ws + alloc((size_t)N*EMBP*2));
  f16* aggr              = (f16*)(ws + alloc((size_t)Mp*EMBP*2));
  unsigned int*  entries = (unsigned int*)(ws + alloc((size_t)EN*4));
  int* rowptr            = (int*)(ws + alloc((size_t)(N+1)*4));
  int* cursor            = (int*)(ws + alloc((size_t)N*4));
  int* deg               = (int*)(ws + alloc((size_t)N*4));
  int* bsum              = (int*)(ws + alloc((size_t)NBLK*4));
  int* boff              = (int*)(ws + alloc((size_t)NBLK*4));
  f16* W1T               = (f16*)(ws + alloc((size_t)NLAYER*HIDP*EMBP*2));
  f16* W2T               = (f16*)(ws + alloc((size_t)NLAYER*EMBP2*HIDP*2));
  float* e1pf            = (float*)(ws + alloc((size_t)NLAYER*6*EMBP*4));
  float* e2pf            = (float*)(ws + alloc((size_t)NLAYER*3*EMBP*4));
  float* b1p             = (float*)(ws + alloc((size_t)NLAYER*HIDP*4));
  float* b2p             = (float*)(ws + alloc((size_t)NLAYER*EMBP*4));
  float* part            = (float*)(ws + alloc((size_t)RB*2*EMBP*4));
  float* scl             = (float*)(ws + alloc((size_t)EMBP*4));
  float* sft             = (float*)(ws + alloc((size_t)EMBP*4));

  if (off >= ws_size) return;
  size_t avail = ws_size - off;
  size_t maxrows = avail / ((size_t)HIDP*2);
  if (maxrows < 128) return;
  int CH = (maxrows >= (size_t)Mp) ? Mp : (int)(maxrows & ~(size_t)127);
  f16* hidc = (f16*)(ws + off);

  // CSR build
  k_zero<<<(N+255)/256, 256, 0, stream>>>((unsigned int*)deg, N);
  k_hist<<<(EN+255)/256, 256, 0, stream>>>(ei, E, N, deg);
  k_scanA<<<NBLK, 256, 0, stream>>>(deg, bsum, N);
  k_scanB<<<1, 64, 0, stream>>>(bsum, boff, rowptr + N, NBLK);
  k_scanC<<<NBLK, 256, 0, stream>>>(deg, boff, rowptr, cursor, N);
  k_fill<<<(EN+255)/256, 256, 0, stream>>>(ei, ea, E, N, cursor, entries);

  // weight/table prep
  {
    int tot1 = NLAYER*HIDP*EMBP;
    k_prep_w<<<(tot1+255)/256, 256, 0, stream>>>(W1, W1T, EMB, HID, EMBP, HIDP);
    int tot2 = NLAYER*EMBP2*HIDP;
    k_prep_w<<<(tot2+255)/256, 256, 0, stream>>>(W2, W2T, HID, EMB, HIDP, EMBP2);
  }
  k_padb<<<((NLAYER*6*EMBP)+255)/256, 256, 0, stream>>>(ee1, e1pf, NLAYER*6, EMB, EMBP);
  k_padb<<<((NLAYER*3*EMBP)+255)/256, 256, 0, stream>>>(ee2, e2pf, NLAYER*3, EMB, EMBP);
  k_padb<<<((NLAYER*HIDP)+255)/256, 256, 0, stream>>>(b1, b1p, NLAYER, HID, HIDP);
  k_padb<<<((NLAYER*EMBP)+255)/256, 256, 0, stream>>>(b2, b2p, NLAYER, EMB, EMBP);

  // h0 f16
  k_h0<<<(N+3)/4, 256, 0, stream>>>(x, xe1, xe2, h, N);

  for (int l = 0; l < NLAYER; ++l) {
    k_aggr<<<Mp/4, 256, 0, stream>>>(h, rowptr, entries,
        e1pf + (size_t)l*6*EMBP, e2pf + (size_t)l*3*EMBP, aggr, N, Mp);

    for (int base = 0; base < Mp; base += CH) {
      const int rows = (Mp - base < CH) ? (Mp - base) : CH;
      dim3 g1(rows/128, HIDP/128);
      k_gemm<EMBP, true><<<g1, 256, 0, stream>>>(
          aggr + (size_t)base*EMBP, W1T + (size_t)l*HIDP*EMBP,
          b1p + (size_t)l*HIDP, hidc, nullptr, base, N);
      dim3 g2(rows/128, EMBP2/128);
      k_gemm<HIDP, false><<<g2, 256, 0, stream>>>(
          hidc, W2T + (size_t)l*EMBP2*HIDP,
          b2p + (size_t)l*EMBP, dout, part, base, N);
    }
    k_bnfin<<<1, EMBP, 0, stream>>>(part, gam + (size_t)l*EMB, bet + (size_t)l*EMB, scl, sft, N, RB);
    if (l < NLAYER - 1) {
      int tot = N * (EMBP/4);
      k_bnapply<<<(tot+255)/256, 256, 0, stream>>>(dout, scl, sft, h, N);
    }
  }
  k_bnlast<<<((N*EMB)+255)/256, 256, 0, stream>>>(dout, scl, sft, N);
}

// Round 10
// 849.688 us; speedup vs baseline: 1.8935x; 1.5462x over previous
//
#include <hip/hip_runtime.h>
#include <stdint.h>

#define NLAYER 5
#define EMB    300
#define EMBP   320
#define EMBP2  384
#define HID    600
#define HIDP   640
#define BNEPS  1e-5f

typedef _Float16 f16;
typedef __attribute__((ext_vector_type(8))) _Float16 hfrag;
typedef __attribute__((ext_vector_type(4))) float f32x4;

__device__ __forceinline__ void gload16(const void* g, void* l){
  __builtin_amdgcn_global_load_lds(
      (const __attribute__((address_space(1))) void*)g,
      (__attribute__((address_space(3))) void*)l,
      16, 0, 0);
}

// ---------------- setup kernels ----------------

__global__ void k_zero(unsigned int* __restrict__ p, int n){
  int i = blockIdx.x*blockDim.x + threadIdx.x;
  if (i < n) p[i] = 0u;
}

__global__ void k_hist(const int* __restrict__ ei, int E, int N, int* __restrict__ deg){
  int e = blockIdx.x*blockDim.x + threadIdx.x;
  if (e >= E + N) return;
  int dst = (e < E) ? ei[E + e] : (e - E);
  atomicAdd(&deg[dst], 1);
}

// ---- 3-phase exclusive scan ----
__global__ void k_scanA(const int* __restrict__ deg, int* __restrict__ bsum, int N){
  __shared__ int sd[256];
  const int tid = threadIdx.x;
  const int base = blockIdx.x*1024 + tid*4;
  int s = 0;
#pragma unroll
  for (int j = 0; j < 4; j++){ int i = base + j; if (i < N) s += deg[i]; }
  sd[tid] = s; __syncthreads();
  for (int off = 128; off > 0; off >>= 1){
    if (tid < off) sd[tid] += sd[tid+off];
    __syncthreads();
  }
  if (tid == 0) bsum[blockIdx.x] = sd[0];
}

__global__ void k_scanB(const int* __restrict__ bsum, int* __restrict__ boff,
                        int* __restrict__ rowptrN, int NBLK){
  const int lane = threadIdx.x;   // 64 threads
  int carry = 0;
  for (int c = 0; c < NBLK; c += 64){
    int idx = c + lane;
    int v = (idx < NBLK) ? bsum[idx] : 0;
    int incl = v;
    for (int off = 1; off < 64; off <<= 1){
      int t = __shfl_up(incl, off);
      if (lane >= off) incl += t;
    }
    if (idx < NBLK) boff[idx] = carry + incl - v;
    carry += __shfl(incl, 63);
  }
  if (lane == 0) *rowptrN = carry;
}

__global__ void k_scanC(const int* __restrict__ deg, const int* __restrict__ boff,
                        int* __restrict__ rowptr, int* __restrict__ cursor, int N){
  __shared__ int ts[256];
  const int tid = threadIdx.x;
  const int base = blockIdx.x*1024 + tid*4;
  int v[4]; int s = 0;
#pragma unroll
  for (int j = 0; j < 4; j++){ int i = base + j; v[j] = (i < N) ? deg[i] : 0; s += v[j]; }
  ts[tid] = s; __syncthreads();
  for (int off = 1; off < 256; off <<= 1){
    int t = (tid >= off) ? ts[tid-off] : 0;
    __syncthreads();
    ts[tid] += t;
    __syncthreads();
  }
  int excl = ((tid > 0) ? ts[tid-1] : 0) + boff[blockIdx.x];
#pragma unroll
  for (int j = 0; j < 4; j++){
    int i = base + j;
    if (i < N){ rowptr[i] = excl; cursor[i] = excl; }
    excl += v[j];
  }
}

__global__ void k_fill(const int* __restrict__ ei, const int* __restrict__ ea,
                       int E, int N, int* __restrict__ cursor,
                       unsigned int* __restrict__ entries)
{
  int e = blockIdx.x*blockDim.x + threadIdx.x;
  if (e >= E + N) return;
  int src, dst, bt, bd;
  if (e < E) { src = ei[e]; dst = ei[E + e]; bt = ea[2*e]; bd = ea[2*e + 1]; }
  else       { src = e - E; dst = src;       bt = 4;       bd = 0; }
  int pos = atomicAdd(&cursor[dst], 1);
  entries[pos] = (unsigned)src | ((unsigned)bt << 20) | ((unsigned)bd << 24);
}

// W: [NLAYER][K][Ncol] f32 -> WT: [NLAYER][Np][Kp] f16 (transposed, zero-padded)
__global__ void k_prep_w(const float* __restrict__ W, f16* __restrict__ WT,
                         int K, int Ncol, int Kp, int Np)
{
  int i = blockIdx.x*blockDim.x + threadIdx.x;
  int total = NLAYER * Np * Kp;
  if (i >= total) return;
  int l = i / (Np * Kp);
  int rem = i - l * (Np * Kp);
  int n = rem / Kp;
  int k = rem - n * Kp;
  f16 v = (f16)0.f;
  if (n < Ncol && k < K) v = (f16)W[(size_t)l*K*Ncol + (size_t)k*Ncol + n];
  WT[i] = v;
}

// [R][SC] f32 -> [R][DC] f32 zero-padded
__global__ void k_padb(const float* __restrict__ src, float* __restrict__ dst,
                       int R, int SC, int DC)
{
  int i = blockIdx.x*blockDim.x + threadIdx.x;
  if (i >= R * DC) return;
  int r = i / DC, c = i - r * DC;
  dst[i] = (c < SC) ? src[r*SC + c] : 0.f;
}

// h0 f16 padded: h[n][c] = f16(xe1[x0][c] + xe2[x1][c])
__global__ void k_h0(const int* __restrict__ x, const float* __restrict__ xe1,
                     const float* __restrict__ xe2, f16* __restrict__ h, int N)
{
  const int w = threadIdx.x >> 6, lane = threadIdx.x & 63;
  const int n = blockIdx.x * 4 + w;
  if (n >= N || lane >= 40) return;
  const int c0 = lane * 8;
  const bool lo = (c0 + 4) <= EMB;
  const bool hi = (c0 + 8) <= EMB;
  const float* r1 = xe1 + (size_t)x[2*n]*EMB + c0;
  const float* r2 = xe2 + (size_t)x[2*n+1]*EMB + c0;
  f32x4 a1 = lo ? *(const f32x4*)r1     : (f32x4){0,0,0,0};
  f32x4 a2 = hi ? *(const f32x4*)(r1+4) : (f32x4){0,0,0,0};
  f32x4 b1 = lo ? *(const f32x4*)r2     : (f32x4){0,0,0,0};
  f32x4 b2 = hi ? *(const f32x4*)(r2+4) : (f32x4){0,0,0,0};
  hfrag o;
#pragma unroll
  for (int j = 0; j < 4; j++){
    o[j]   = (f16)(a1[j] + b1[j]);
    o[4+j] = (f16)(a2[j] + b2[j]);
  }
  *(hfrag*)&h[(size_t)n*EMBP + c0] = o;
}

// ---------------- aggregation: one wave per node, f16 h gather ----------------
// 8-wide predicated batches (wave-uniform mask): 1 latency round for deg<=8 (~93%).
__global__ __launch_bounds__(256) void k_aggr(
    const f16* __restrict__ h,                  // [N][EMBP] f16
    const int* __restrict__ rowptr,
    const unsigned int* __restrict__ entries,
    const float* __restrict__ t1,               // [6][EMBP] f32 padded
    const float* __restrict__ t2,               // [3][EMBP] f32 padded
    f16* __restrict__ aggr, int N, int Mp)
{
  const int w = threadIdx.x >> 6, lane = threadIdx.x & 63;
  const int n = blockIdx.x * 4 + w;
  if (n >= Mp || lane >= 40) return;
  const int c0 = lane * 8;
  float s[8] = {0.f,0.f,0.f,0.f,0.f,0.f,0.f,0.f};
  if (n < N) {
    const int beg = rowptr[n], end = rowptr[n+1];
    int c6[6] = {0,0,0,0,0,0};
    int c3[3] = {0,0,0};
    for (int b0 = beg; b0 < end; b0 += 8) {
      unsigned pe[8]; bool vl[8];
#pragma unroll
      for (int j = 0; j < 8; j++){
        const int idx = b0 + j;
        vl[j] = idx < end;                 // wave-uniform
        pe[j] = entries[vl[j] ? idx : beg];
      }
      hfrag v[8];
#pragma unroll
      for (int j = 0; j < 8; j++)
        v[j] = *(const hfrag*)&h[(size_t)(pe[j] & 0xFFFFF)*EMBP + c0];
#pragma unroll
      for (int j = 0; j < 8; j++){
        if (vl[j]){
          const int bt = (pe[j] >> 20) & 7, bd = (pe[j] >> 24) & 3;
#pragma unroll
          for (int t = 0; t < 6; t++) c6[t] += (bt == t);
#pragma unroll
          for (int t = 0; t < 3; t++) c3[t] += (bd == t);
#pragma unroll
          for (int k = 0; k < 8; k++) s[k] += (float)v[j][k];
        }
      }
    }
#pragma unroll
    for (int t = 0; t < 6; t++) if (c6[t]) {
      const float f = (float)c6[t];
      f32x4 a = *(const f32x4*)&t1[t*EMBP + c0];
      f32x4 b = *(const f32x4*)&t1[t*EMBP + c0 + 4];
#pragma unroll
      for (int k = 0; k < 4; k++){ s[k] += f*a[k]; s[4+k] += f*b[k]; }
    }
#pragma unroll
    for (int t = 0; t < 3; t++) if (c3[t]) {
      const float f = (float)c3[t];
      f32x4 a = *(const f32x4*)&t2[t*EMBP + c0];
      f32x4 b = *(const f32x4*)&t2[t*EMBP + c0 + 4];
#pragma unroll
      for (int k = 0; k < 4; k++){ s[k] += f*a[k]; s[4+k] += f*b[k]; }
    }
  }
  hfrag o;
#pragma unroll
  for (int j = 0; j < 8; j++) o[j] = (f16)s[j];
  *(hfrag*)&aggr[(size_t)n*EMBP + c0] = o;
}

// ---------------- GEMM: 128x128 tile, BK=64, double-buffered, counted vmcnt ----
// FIRST: C = f16 relu -> hid (stride HIDP, chunk-local). else: C = f32 d_out,
// masked, + fused deterministic BN partial stats per (rowblock, colblock).
template<int KP, bool FIRST>
__global__ __launch_bounds__(256) void k_gemm(
    const f16* __restrict__ A,
    const f16* __restrict__ Bt,
    const float* __restrict__ bias,
    void* __restrict__ Cv,
    float* __restrict__ part,
    int nBase, int N)
{
  constexpr int NT = KP / 64;
  __shared__ __align__(16) f16 As[2][128*64];
  __shared__ __align__(16) f16 Bs[2][128*64];
  __shared__ float redS[4][64];
  __shared__ float redQ[4][64];
  const int tid = threadIdx.x;
  const int w = tid >> 6, lane = tid & 63;
  const int wr = w >> 1, wc = w & 1;
  const int m0 = blockIdx.x * 128;
  const int n0 = blockIdx.y * 128;
  const int cl = lane & 15, kg = lane >> 4;

  // 4 rounds x 256 threads cover 128 rows x 8 segs (16B). LDS dest linear;
  // global source pre-swizzled seg_g = seg ^ (row&7) (both-sides, rule #21).
  const f16* ag[4]; const f16* bg[4]; int ldst[4];
#pragma unroll
  for (int i = 0; i < 4; i++){
    const int id = i*256 + tid;
    const int row = id >> 3, seg = id & 7;
    const int col = (seg ^ (row & 7)) * 8;
    ag[i] = A  + (size_t)(m0 + row)*KP + col;
    bg[i] = Bt + (size_t)(n0 + row)*KP + col;
    ldst[i] = id * 8;
  }

  auto STAGE = [&](int bb, int kt){
    const int k0 = kt*64;
#pragma unroll
    for (int i = 0; i < 4; i++) gload16(ag[i] + k0, &As[bb][ldst[i]]);
#pragma unroll
    for (int i = 0; i < 4; i++) gload16(bg[i] + k0, &Bs[bb][ldst[i]]);
  };

  f32x4 acc[4][4];
#pragma unroll
  for (int i = 0; i < 4; i++)
#pragma unroll
    for (int j = 0; j < 4; j++)
      acc[i][j] = (f32x4){0.f, 0.f, 0.f, 0.f};

  STAGE(0, 0);
#pragma unroll
  for (int t = 0; t < NT; ++t){
    const int cur = t & 1;
    if (t + 1 < NT){
      STAGE(cur ^ 1, t + 1);                       // prefetch stays in flight
      asm volatile("s_waitcnt vmcnt(8)" ::: "memory");   // only tile t drained
    } else {
      asm volatile("s_waitcnt vmcnt(0)" ::: "memory");
    }
    __builtin_amdgcn_s_barrier();                  // raw: no vmcnt(0) drain
    hfrag af[4][2], bf[4][2];
#pragma unroll
    for (int mf = 0; mf < 4; mf++){
      const int row = wr*64 + mf*16 + cl;
#pragma unroll
      for (int hh = 0; hh < 2; hh++)
        af[mf][hh] = *(const hfrag*)&As[cur][row*64 + (((kg + 4*hh) ^ (cl & 7)) * 8)];
    }
#pragma unroll
    for (int nf = 0; nf < 4; nf++){
      const int row = wc*64 + nf*16 + cl;
#pragma unroll
      for (int hh = 0; hh < 2; hh++)
        bf[nf][hh] = *(const hfrag*)&Bs[cur][row*64 + (((kg + 4*hh) ^ (cl & 7)) * 8)];
    }
#pragma unroll
    for (int mf = 0; mf < 4; mf++)
#pragma unroll
      for (int nf = 0; nf < 4; nf++){
        acc[mf][nf] = __builtin_amdgcn_mfma_f32_16x16x32_f16(af[mf][0], bf[nf][0], acc[mf][nf], 0, 0, 0);
        acc[mf][nf] = __builtin_amdgcn_mfma_f32_16x16x32_f16(af[mf][1], bf[nf][1], acc[mf][nf], 0, 0, 0);
      }
    __builtin_amdgcn_s_barrier();                  // reads of buf done before re-stage
  }

  const int rg = lane >> 4;
  float ps[4] = {0.f,0.f,0.f,0.f}, pq[4] = {0.f,0.f,0.f,0.f};
#pragma unroll
  for (int mf = 0; mf < 4; mf++) {
#pragma unroll
    for (int nf = 0; nf < 4; nf++) {
      const int col  = n0 + wc*64 + nf*16 + cl;
      const int row0 = m0 + wr*64 + mf*16 + rg*4;
      f32x4 v = acc[mf][nf];
      if (FIRST) {
        const float bv = bias[col];
#pragma unroll
        for (int r = 0; r < 4; r++)
          ((f16*)Cv)[(size_t)(row0 + r)*HIDP + col] = (f16)fmaxf(v[r] + bv, 0.f);
      } else {
        const float bv = bias[col];
#pragma unroll
        for (int r = 0; r < 4; r++) {
          const int grow = nBase + row0 + r;
          if (grow < N) {
            const float o = v[r] + bv;
            if (col < EMB) ((float*)Cv)[(size_t)grow*EMB + col] = o;
            ps[nf] += o; pq[nf] += o*o;
          }
        }
      }
    }
  }

  if (!FIRST) {
    // deterministic reduce: shfl tree over rg, LDS over wr, write per-(gb,colblock)
#pragma unroll
    for (int nf = 0; nf < 4; nf++){
      float s1 = ps[nf], q1 = pq[nf];
      s1 += __shfl_xor(s1, 16); q1 += __shfl_xor(q1, 16);
      s1 += __shfl_xor(s1, 32); q1 += __shfl_xor(q1, 32);
      if (rg == 0){ redS[w][nf*16 + cl] = s1; redQ[w][nf*16 + cl] = q1; }
    }
    __syncthreads();
    if (w < 2 && lane < 16){
      const int gb = (nBase + m0) >> 7;
      float* pS = part + (size_t)gb * (2*EMBP);
#pragma unroll
      for (int nf = 0; nf < 4; nf++){
        const int lc  = nf*16 + lane;
        const int col = n0 + w*64 + nf*16 + lane;
        if (col < EMBP){
          pS[col]        = redS[w][lc] + redS[w+2][lc];
          pS[EMBP + col] = redQ[w][lc] + redQ[w+2][lc];
        }
      }
    }
  }
}

// ---------------- BN finalize (parallel: one block per column) ----------------

__global__ __launch_bounds__(256) void k_bnfin(
    const float* __restrict__ part,
    const float* __restrict__ gamma,
    const float* __restrict__ beta,
    float* __restrict__ scl, float* __restrict__ sft, int N, int RB)
{
  __shared__ float rs[256], rq[256];
  const int c = blockIdx.x;          // 0..EMBP-1
  const int t = threadIdx.x;
  float s = 0.f, q = 0.f;
  for (int gb = t; gb < RB; gb += 256){
    s += part[(size_t)gb*(2*EMBP) + c];
    q += part[(size_t)gb*(2*EMBP) + EMBP + c];
  }
  rs[t] = s; rq[t] = q; __syncthreads();
  for (int off = 128; off > 0; off >>= 1){
    if (t < off){ rs[t] += rs[t+off]; rq[t] += rq[t+off]; }
    __syncthreads();
  }
  if (t == 0){
    if (c < EMB){
      float mean = rs[0] / (float)N;
      float var  = fmaxf(rq[0] / (float)N - mean*mean, 0.f);
      float sc = gamma[c] * rsqrtf(var + BNEPS);
      scl[c] = sc;
      sft[c] = beta[c] - mean*sc;
    } else { scl[c] = 0.f; sft[c] = 0.f; }
  }
}

// mid layers: h[n][c] = f16(relu(dout*scl+sft)), pad cols zero
__global__ void k_bnapply(const float* __restrict__ outv,
                          const float* __restrict__ scl, const float* __restrict__ sft,
                          f16* __restrict__ h, int N)
{
  int i = blockIdx.x*blockDim.x + threadIdx.x;
  if (i >= N * (EMBP/4)) return;
  const int n = i / (EMBP/4);
  const int c = (i - n*(EMBP/4)) * 4;
  f16 o[4];
  if (c < EMB) {   // EMB%4==0: segments fully in or out
    f32x4 v = *(const f32x4*)&outv[(size_t)n*EMB + c];
#pragma unroll
    for (int j = 0; j < 4; j++) o[j] = (f16)fmaxf(v[j]*scl[c+j] + sft[c+j], 0.f);
  } else {
#pragma unroll
    for (int j = 0; j < 4; j++) o[j] = (f16)0.f;
  }
  *(unsigned long long*)&h[(size_t)n*EMBP + c] = *(const unsigned long long*)o;
}

// last layer: dout = dout*scl + sft (no relu), in place
__global__ void k_bnlast(float* __restrict__ out, const float* __restrict__ scl,
                         const float* __restrict__ sft, int N){
  int i = blockIdx.x*blockDim.x + threadIdx.x;
  if (i >= N*EMB) return;
  int c = i % EMB;
  out[i] = out[i]*scl[c] + sft[c];
}

// ---------------- host ----------------

extern "C" void kernel_launch(void* const* d_in, const int* in_sizes, int n_in,
                              void* d_out, int out_size, void* d_ws, size_t ws_size,
                              hipStream_t stream)
{
  (void)n_in; (void)out_size;
  const int* x  = (const int*)d_in[0];
  const int* ei = (const int*)d_in[1];
  const int* ea = (const int*)d_in[2];
  const float* xe1 = (const float*)d_in[3];
  const float* xe2 = (const float*)d_in[4];
  const float* ee1 = (const float*)d_in[5];
  const float* ee2 = (const float*)d_in[6];
  const float* W1  = (const float*)d_in[7];
  const float* b1  = (const float*)d_in[8];
  const float* W2  = (const float*)d_in[9];
  const float* b2  = (const float*)d_in[10];
  const float* gam = (const float*)d_in[11];
  const float* bet = (const float*)d_in[12];

  const int N  = in_sizes[0] / 2;
  const int E  = in_sizes[1] / 2;
  const int EN = E + N;
  const int Mp = ((N + 127) / 128) * 128;
  const int RB = Mp / 128;
  const int NBLK = (N + 1023) / 1024;

  float* dout = (float*)d_out;

  char* ws = (char*)d_ws;
  size_t off = 0;
  auto alloc = [&](size_t bytes){ size_t o = off; off = (off + bytes + 255) & ~(size_t)255; return o; };

  f16* h                 = (f16*)(ws + alloc((size_t)N*EMBP*2));
  f16* aggr              = (f16*)(ws + alloc((size_t)Mp*EMBP*2));
  unsigned int*  entries = (unsigned int*)(ws + alloc((size_t)EN*4));
  int* rowptr            = (int*)(ws + alloc((size_t)(N+1)*4));
  int* cursor            = (int*)(ws + alloc((size_t)N*4));
  int* deg               = (int*)(ws + alloc((size_t)N*4));
  int* bsum              = (int*)(ws + alloc((size_t)NBLK*4));
  int* boff              = (int*)(ws + alloc((size_t)NBLK*4));
  f16* W1T               = (f16*)(ws + alloc((size_t)NLAYER*HIDP*EMBP*2));
  f16* W2T               = (f16*)(ws + alloc((size_t)NLAYER*EMBP2*HIDP*2));
  float* e1pf            = (float*)(ws + alloc((size_t)NLAYER*6*EMBP*4));
  float* e2pf            = (float*)(ws + alloc((size_t)NLAYER*3*EMBP*4));
  float* b1p             = (float*)(ws + alloc((size_t)NLAYER*HIDP*4));
  float* b2p             = (float*)(ws + alloc((size_t)NLAYER*EMBP*4));
  float* part            = (float*)(ws + alloc((size_t)RB*2*EMBP*4));
  float* scl             = (float*)(ws + alloc((size_t)EMBP*4));
  float* sft             = (float*)(ws + alloc((size_t)EMBP*4));

  if (off >= ws_size) return;
  size_t avail = ws_size - off;
  size_t maxrows = avail / ((size_t)HIDP*2);
  if (maxrows < 128) return;
  int CH = (maxrows >= (size_t)Mp) ? Mp : (int)(maxrows & ~(size_t)127);
  f16* hidc = (f16*)(ws + off);

  // CSR build
  k_zero<<<(N+255)/256, 256, 0, stream>>>((unsigned int*)deg, N);
  k_hist<<<(EN+255)/256, 256, 0, stream>>>(ei, E, N, deg);
  k_scanA<<<NBLK, 256, 0, stream>>>(deg, bsum, N);
  k_scanB<<<1, 64, 0, stream>>>(bsum, boff, rowptr + N, NBLK);
  k_scanC<<<NBLK, 256, 0, stream>>>(deg, boff, rowptr, cursor, N);
  k_fill<<<(EN+255)/256, 256, 0, stream>>>(ei, ea, E, N, cursor, entries);

  // weight/table prep
  {
    int tot1 = NLAYER*HIDP*EMBP;
    k_prep_w<<<(tot1+255)/256, 256, 0, stream>>>(W1, W1T, EMB, HID, EMBP, HIDP);
    int tot2 = NLAYER*EMBP2*HIDP;
    k_prep_w<<<(tot2+255)/256, 256, 0, stream>>>(W2, W2T, HID, EMB, HIDP, EMBP2);
  }
  k_padb<<<((NLAYER*6*EMBP)+255)/256, 256, 0, stream>>>(ee1, e1pf, NLAYER*6, EMB, EMBP);
  k_padb<<<((NLAYER*3*EMBP)+255)/256, 256, 0, stream>>>(ee2, e2pf, NLAYER*3, EMB, EMBP);
  k_padb<<<((NLAYER*HIDP)+255)/256, 256, 0, stream>>>(b1, b1p, NLAYER, HID, HIDP);
  k_padb<<<((NLAYER*EMBP)+255)/256, 256, 0, stream>>>(b2, b2p, NLAYER, EMB, EMBP);

  // h0 f16
  k_h0<<<(N+3)/4, 256, 0, stream>>>(x, xe1, xe2, h, N);

  for (int l = 0; l < NLAYER; ++l) {
    k_aggr<<<Mp/4, 256, 0, stream>>>(h, rowptr, entries,
        e1pf + (size_t)l*6*EMBP, e2pf + (size_t)l*3*EMBP, aggr, N, Mp);

    for (int base = 0; base < Mp; base += CH) {
      const int rows = (Mp - base < CH) ? (Mp - base) : CH;
      dim3 g1(rows/128, HIDP/128);
      k_gemm<EMBP, true><<<g1, 256, 0, stream>>>(
          aggr + (size_t)base*EMBP, W1T + (size_t)l*HIDP*EMBP,
          b1p + (size_t)l*HIDP, hidc, nullptr, base, N);
      dim3 g2(rows/128, EMBP2/128);
      k_gemm<HIDP, false><<<g2, 256, 0, stream>>>(
          hidc, W2T + (size_t)l*EMBP2*HIDP,
          b2p + (size_t)l*EMBP, dout, part, base, N);
    }
    k_bnfin<<<EMBP, 256, 0, stream>>>(part, gam + (size_t)l*EMB, bet + (size_t)l*EMB, scl, sft, N, RB);
    if (l < NLAYER - 1) {
      int tot = N * (EMBP/4);
      k_bnapply<<<(tot+255)/256, 256, 0, stream>>>(dout, scl, sft, h, N);
    }
  }
  k_bnlast<<<((N*EMB)+255)/256, 256, 0, stream>>>(dout, scl, sft, N);
}